// Round 1
// baseline (318.165 us; speedup 1.0000x reference)
//
#include <hip/hip_runtime.h>
#include <hip/hip_bf16.h>
#include <math.h>

#define SEQ 16
#define LATENT 2048
#define HID 1024
#define G4 4096  // 4*HID

// ---------------------------------------------------------------------------
// xg[t][g] = sum_d x[t][d] * w[g][d] + b_ih[g] + b_hh[g]
// One block per g (4096 blocks, 256 threads). w row read once, reused for all
// 16 timesteps (x is tiny and L1/L2-resident).
// ---------------------------------------------------------------------------
__global__ void xg_gemm(const float* __restrict__ x,     // [SEQ][K]
                        const float* __restrict__ w,     // [4096][K]
                        const float* __restrict__ b_ih,  // [4096]
                        const float* __restrict__ b_hh,  // [4096]
                        float* __restrict__ xg,          // [SEQ][4096]
                        int K) {
    const int g    = blockIdx.x;
    const int tid  = threadIdx.x;
    const int wave = tid >> 6;
    const int lane = tid & 63;

    float acc[SEQ];
#pragma unroll
    for (int t = 0; t < SEQ; ++t) acc[t] = 0.f;

    const float* wrow = w + (size_t)g * K;
    const int per = K >> 8;  // 8 for K=2048, 4 for K=1024
    for (int e = 0; e < per; ++e) {
        const int d = tid + (e << 8);
        const float wv = wrow[d];
#pragma unroll
        for (int t = 0; t < SEQ; ++t) acc[t] += wv * x[t * K + d];
    }

    __shared__ float red[4][SEQ];
#pragma unroll
    for (int t = 0; t < SEQ; ++t) {
        float v = acc[t];
        for (int off = 32; off; off >>= 1) v += __shfl_down(v, off);
        if (lane == 0) red[wave][t] = v;
    }
    __syncthreads();
    if (tid < SEQ) {
        const int t = tid;
        const float s = red[0][t] + red[1][t] + red[2][t] + red[3][t];
        xg[t * G4 + g] = s + b_ih[g] + b_hh[g];
    }
}

// ---------------------------------------------------------------------------
// One LSTM recurrent step. Block b owns hidden index j = blockIdx.x.
// Wave k (k=0..3) computes gate k's dot:  sum_j' w_hh[k*HID + j][j'] * h[j'].
// Then thread 0 applies activations, updates c, writes h.
// h_prev == nullptr / c_prev == nullptr encode t==0 (zero state).
// ---------------------------------------------------------------------------
__global__ void lstm_step(const float* __restrict__ w_hh,   // [4096][1024]
                          const float* __restrict__ xg_t,   // [4096]
                          const float* __restrict__ h_prev, // [1024] or null
                          const float* __restrict__ c_prev, // [1024] or null
                          float* __restrict__ c_out,        // [1024]
                          float* __restrict__ h_out,        // [1024]
                          float* __restrict__ h_out2) {     // [1024] or null
    const int j    = blockIdx.x;
    const int tid  = threadIdx.x;
    const int wave = tid >> 6;
    const int lane = tid & 63;

    __shared__ float hs[HID];
    __shared__ float gate_s[4];

    float gacc = 0.f;
    if (h_prev != nullptr) {
        for (int i = tid; i < HID; i += 256) hs[i] = h_prev[i];
        __syncthreads();
        const float* wrow = w_hh + (size_t)(wave * HID + j) * HID;
        const float4* w4 = (const float4*)wrow;
        const float4* h4 = (const float4*)hs;
        float acc = 0.f;
#pragma unroll
        for (int e = 0; e < 4; ++e) {
            const float4 wv = w4[lane + (e << 6)];
            const float4 hv = h4[lane + (e << 6)];
            acc += wv.x * hv.x + wv.y * hv.y + wv.z * hv.z + wv.w * hv.w;
        }
        for (int off = 32; off; off >>= 1) acc += __shfl_down(acc, off);
        gacc = acc;
    }
    if (lane == 0) gate_s[wave] = gacc;
    __syncthreads();

    if (tid == 0) {
        float i_ = xg_t[j]          + gate_s[0];
        float f_ = xg_t[j + HID]    + gate_s[1];
        float g_ = xg_t[j + 2*HID]  + gate_s[2];
        float o_ = xg_t[j + 3*HID]  + gate_s[3];
        i_ = 1.f / (1.f + expf(-i_));
        f_ = 1.f / (1.f + expf(-f_));
        g_ = tanhf(g_);
        o_ = 1.f / (1.f + expf(-o_));
        const float cp = (c_prev != nullptr) ? c_prev[j] : 0.f;
        const float c_ = f_ * cp + i_ * g_;
        const float h_ = o_ * tanhf(c_);
        c_out[j] = c_;
        h_out[j] = h_;
        if (h_out2 != nullptr) h_out2[j] = h_;
    }
}

extern "C" void kernel_launch(void* const* d_in, const int* in_sizes, int n_in,
                              void* d_out, int out_size, void* d_ws, size_t ws_size,
                              hipStream_t stream) {
    const float* x     = (const float*)d_in[0];
    const float* w_ih0 = (const float*)d_in[1];
    const float* w_hh0 = (const float*)d_in[2];
    const float* b_ih0 = (const float*)d_in[3];
    const float* b_hh0 = (const float*)d_in[4];
    const float* w_ih1 = (const float*)d_in[5];
    const float* w_hh1 = (const float*)d_in[6];
    const float* b_ih1 = (const float*)d_in[7];
    const float* b_hh1 = (const float*)d_in[8];

    float* xg = (float*)d_ws;           // SEQ*4096 = 65536 floats
    float* h1 = xg + SEQ * G4;          // SEQ*1024 = 16384 floats
    float* c  = h1 + SEQ * HID;         // 1024 floats

    float* last = (float*)d_out;        // [1024]
    float* h2   = last + HID;           // [SEQ][1024]

    // ---- layer 0 ----
    xg_gemm<<<G4, 256, 0, stream>>>(x, w_ih0, b_ih0, b_hh0, xg, LATENT);
    for (int t = 0; t < SEQ; ++t) {
        const float* hp = (t == 0) ? nullptr : (h1 + (t - 1) * HID);
        const float* cp = (t == 0) ? nullptr : c;
        lstm_step<<<HID, 256, 0, stream>>>(w_hh0, xg + t * G4, hp, cp,
                                           c, h1 + t * HID, nullptr);
    }

    // ---- layer 1 ----
    xg_gemm<<<G4, 256, 0, stream>>>(h1, w_ih1, b_ih1, b_hh1, xg, HID);
    for (int t = 0; t < SEQ; ++t) {
        const float* hp = (t == 0) ? nullptr : (h2 + (t - 1) * HID);
        const float* cp = (t == 0) ? nullptr : c;
        lstm_step<<<HID, 256, 0, stream>>>(w_hh1, xg + t * G4, hp, cp,
                                           c, h2 + t * HID,
                                           (t == 15) ? last : nullptr);
    }
}